// Round 8
// baseline (16694.926 us; speedup 1.0000x reference)
//
#include <hip/hip_runtime.h>
#include <hip/hip_bf16.h>
#include <cstdint>
#include <cstddef>

typedef short bf16x8 __attribute__((ext_vector_type(8)));
typedef float f32x4  __attribute__((ext_vector_type(4)));
typedef unsigned int u32x4 __attribute__((ext_vector_type(4)));
typedef __hip_bfloat16 bf16;

#define NT_T 512
#define NB   64
#define NI   512
#define NH   1024
#define NO   512

// h history slots: 64x1024 bf16 + 128-element pad (slot-aligned, no line straddle)
static constexpr size_t SLOT_E = (size_t)NB * NH + 128;
static constexpr size_t SLOT_B = SLOT_E * 2;

// ---------------- workspace layout (bytes, all 256-aligned) ----------------
static constexpr size_t OFF_XBF   = 0;
static constexpr size_t SZ_XBF    = (size_t)NT_T * NB * NI * 2;
static constexpr size_t OFF_WSW0  = OFF_XBF + SZ_XBF;
static constexpr size_t SZ_WSW0   = 128ull * 98304;
static constexpr size_t OFF_WSW1  = OFF_WSW0 + SZ_WSW0;
static constexpr size_t SZ_WSW1   = 128ull * 131072;
static constexpr size_t OFF_WOUT  = OFF_WSW1 + SZ_WSW1;
static constexpr size_t SZ_WOUT   = (size_t)NO * NH * 2;
static constexpr size_t OFF_B0    = OFF_WOUT + SZ_WOUT;
static constexpr size_t OFF_B1    = OFF_B0 + 4096 * 4;
static constexpr size_t OFF_H1    = OFF_B1 + 4096 * 4;
static constexpr size_t SZ_H1     = (size_t)NT_T * SLOT_B;
static constexpr size_t OFF_H2    = OFF_H1 + SZ_H1;
static constexpr size_t SZ_H2     = (size_t)NT_T * SLOT_B;
// flags[layer(2)][blk(128)][t(512)] ushort, producer-private lines.
// R8: flags are HINTS only (fired without drain); data completeness is
// verified consumer-side via the 0xFFFFFFFF sentinel (two bf16 NaNs -- the
// cell output h=sigm(o)*tanh(c) is finite and can never produce it).
static constexpr size_t OFF_FLG   = OFF_H2 + SZ_H2;
static constexpr size_t SZ_FLG    = 2ull * 128 * 512 * 2;   // 256 KB
// total ~198.7 MB

__device__ __forceinline__ float sigm(float x) {
  return 1.0f / (1.0f + __expf(-x));
}
__device__ __forceinline__ float tanh_fast(float x) {
  x = fminf(15.0f, fmaxf(-15.0f, x));
  const float e = __expf(2.0f * x);
  return (e - 1.0f) / (e + 1.0f);
}

// Per-wave flag waits (R3-proven). Agent-scope loads are served fresh from the
// coherence point. Trailing compiler fence keeps subsequent cached bulk
// h-loads from hoisting above the observed flag.
__device__ __forceinline__ void waitf1(const unsigned short* f) {
  while (!__all(__hip_atomic_load(f, __ATOMIC_RELAXED, __HIP_MEMORY_SCOPE_AGENT) != 0))
    __builtin_amdgcn_s_sleep(1);
  asm volatile("" ::: "memory");
}
__device__ __forceinline__ void waitf2(const unsigned short* f0, const unsigned short* f1) {
  while (true) {
    const int a = __hip_atomic_load(f0, __ATOMIC_RELAXED, __HIP_MEMORY_SCOPE_AGENT);
    const int b = __hip_atomic_load(f1, __ATOMIC_RELAXED, __HIP_MEMORY_SCOPE_AGENT);
    if (__all((a != 0) && (b != 0))) break;
    __builtin_amdgcn_s_sleep(1);
  }
  asm volatile("" ::: "memory");
}

// plain batch load of N k-slices (2 row-fragments each) -- R3-proven codegen
template <int N>
__device__ __forceinline__ void load_batch(bf16x8 (&A)[N][2], const bf16* p0, const bf16* p1) {
#pragma unroll
  for (int i = 0; i < N; ++i) {
    A[i][0] = *(const bf16x8*)(p0 + i * 32);
    A[i][1] = *(const bf16x8*)(p1 + i * 32);
  }
}

// Sentinel validation + repair. Fast path: aggregate 4 compares/frag, one
// __any. Slow path (rare: flag beat a laggard producer wave's stores):
// re-load the bad fragment's 4 dwords agent-scope (bypasses the poisoned L2
// line; served fresh from the coherence point) until clean. Termination:
// producers write every fragment unconditionally.
template <int N>
__device__ __forceinline__ void validate_tile(bf16x8 (&A)[N][2],
                                              const bf16* p0, const bf16* p1) {
  unsigned agg = 0;
#pragma unroll
  for (int i = 0; i < N; ++i)
#pragma unroll
    for (int r = 0; r < 2; ++r) {
      const u32x4 d = __builtin_bit_cast(u32x4, A[i][r]);
      agg |= (unsigned)(d[0] == 0xFFFFFFFFu) | (unsigned)(d[1] == 0xFFFFFFFFu) |
             (unsigned)(d[2] == 0xFFFFFFFFu) | (unsigned)(d[3] == 0xFFFFFFFFu);
    }
  if (!__any(agg != 0)) return;
  // slow path: per-fragment agent-scope repair
  for (int i = 0; i < N; ++i)
    for (int r = 0; r < 2; ++r) {
      const unsigned* q = (const unsigned*)((r ? p1 : p0) + i * 32);
      while (true) {
        const u32x4 d = __builtin_bit_cast(u32x4, A[i][r]);
        const bool bad = (d[0] == 0xFFFFFFFFu) | (d[1] == 0xFFFFFFFFu) |
                         (d[2] == 0xFFFFFFFFu) | (d[3] == 0xFFFFFFFFu);
        if (!__any(bad)) break;
        if (bad) {
          u32x4 nd;
          nd[0] = __hip_atomic_load(q + 0, __ATOMIC_RELAXED, __HIP_MEMORY_SCOPE_AGENT);
          nd[1] = __hip_atomic_load(q + 1, __ATOMIC_RELAXED, __HIP_MEMORY_SCOPE_AGENT);
          nd[2] = __hip_atomic_load(q + 2, __ATOMIC_RELAXED, __HIP_MEMORY_SCOPE_AGENT);
          nd[3] = __hip_atomic_load(q + 3, __ATOMIC_RELAXED, __HIP_MEMORY_SCOPE_AGENT);
          A[i][r] = __builtin_bit_cast(bf16x8, nd);
        }
        __builtin_amdgcn_s_sleep(1);
      }
    }
  asm volatile("" ::: "memory");
}

template <int N, int KSW>
__device__ __forceinline__ void mfma_batch(f32x4 (&acc)[2][2], const bf16x8 (&A)[N][2],
                                           const char* Wlds, int ksbase, int lane) {
#pragma unroll
  for (int i = 0; i < N; ++i) {
#pragma unroll
    for (int nt = 0; nt < 2; ++nt) {
      const bf16x8 b = *(const bf16x8*)(Wlds + ((size_t)(nt * KSW + ksbase + i) * 64 + lane) * 16);
      acc[0][nt] = __builtin_amdgcn_mfma_f32_16x16x32_bf16(A[i][0], b, acc[0][nt], 0, 0, 0);
      acc[1][nt] = __builtin_amdgcn_mfma_f32_16x16x32_bf16(A[i][1], b, acc[1][nt], 0, 0, 0);
    }
  }
}

// ---------------- prep kernels ----------------
__global__ void k_convert_x(const float* __restrict__ x, bf16* __restrict__ xbf) {
  const size_t n = (size_t)NT_T * NB * NI;
  for (size_t i = (size_t)blockIdx.x * blockDim.x + threadIdx.x; i < n;
       i += (size_t)gridDim.x * blockDim.x)
    xbf[i] = __float2bfloat16(x[i]);
}

// sentinel-fill the h history region
__global__ void k_fill(u32x4* __restrict__ p, size_t n16) {
  const u32x4 s = {0xFFFFFFFFu, 0xFFFFFFFFu, 0xFFFFFFFFu, 0xFFFFFFFFu};
  for (size_t i = (size_t)blockIdx.x * blockDim.x + threadIdx.x; i < n16;
       i += (size_t)gridDim.x * blockDim.x)
    p[i] = s;
}

// Per-block, per-lane fragment-ordered weight images.
// B-fragment of mfma_f32_16x16x32_bf16: lane l holds B[n = l&15][k = (l>>4)*8 + j].
// Layout: [blk][nt(2)][ks][lane(64)][j(8)]; K-concat: L0 [W_ih0|W_hh0] ks 0..47,
// L1 [W_ih1|W_hh1] ks 0..63. Gate rows per block: [i f g o] x 8 cols at blk*8.
__global__ void k_build_wsw(const float* __restrict__ Wih0, const float* __restrict__ Whh0,
                            const float* __restrict__ Wih1, const float* __restrict__ Whh1,
                            bf16* __restrict__ wsw0, bf16* __restrict__ wsw1) {
  const size_t L0N = 128ull * 2 * 48 * 64 * 8;
  const size_t L1N = 128ull * 2 * 64 * 64 * 8;
  const size_t n = L0N + L1N;
  for (size_t i = (size_t)blockIdx.x * blockDim.x + threadIdx.x; i < n;
       i += (size_t)gridDim.x * blockDim.x) {
    if (i < L0N) {
      size_t idx = i;
      const int j = idx & 7;    idx >>= 3;
      const int lane = idx & 63; idx >>= 6;
      const int ks = (int)(idx % 48); idx /= 48;
      const int nt = idx & 1;
      const int blk = (int)(idx >> 1);
      const int nl = nt * 16 + (lane & 15);
      const int k = ks * 32 + (lane >> 4) * 8 + j;
      const int grow = (nl >> 3) * 1024 + blk * 8 + (nl & 7);
      const float v = (k < 512) ? Wih0[(size_t)grow * 512 + k]
                                : Whh0[(size_t)grow * 1024 + (k - 512)];
      wsw0[i] = __float2bfloat16(v);
    } else {
      size_t idx = i - L0N;
      const size_t o = idx;
      const int j = idx & 7;    idx >>= 3;
      const int lane = idx & 63; idx >>= 6;
      const int ks = (int)(idx % 64); idx /= 64;
      const int nt = idx & 1;
      const int blk = (int)(idx >> 1);
      const int nl = nt * 16 + (lane & 15);
      const int k = ks * 32 + (lane >> 4) * 8 + j;
      const int grow = (nl >> 3) * 1024 + blk * 8 + (nl & 7);
      const float v = (k < 1024) ? Wih1[(size_t)grow * 1024 + k]
                                 : Whh1[(size_t)grow * 1024 + (k - 1024)];
      wsw1[o] = __float2bfloat16(v);
    }
  }
}

__global__ void k_small(const float* __restrict__ Wout,
                        const float* __restrict__ bih0, const float* __restrict__ bhh0,
                        const float* __restrict__ bih1, const float* __restrict__ bhh1,
                        bf16* __restrict__ woutbf, float* __restrict__ bias0,
                        float* __restrict__ bias1, unsigned int* __restrict__ flg) {
  const int i = blockIdx.x * 256 + threadIdx.x;
  if (i < NO * NH) woutbf[i] = __float2bfloat16(Wout[i]);
  if (i < 4096) {
    bias0[i] = bih0[i] + bhh0[i];
    bias1[i] = bih1[i] + bhh1[i];
  }
  if (i < (int)(SZ_FLG / 4)) flg[i] = 0u;  // zero the flag region
}

// ---------------- persistent fused 2-layer LSTM recurrence ----------------
// grid = 256 x 256, 1 block/CU. blocks 0..127: layer0, 128..255: layer1.
// R8 protocol: producer-private HINT flags fired WITHOUT a drain (the vmcnt(0)
// wait before the flag was ~1-1.5us of the critical chain). Consumers detect
// via the hint, bulk-load plainly (L2-cached), then sentinel-validate every
// fragment; rare in-flight stragglers are repaired with agent-scope dword
// loads (which bypass the poisoned L2 line). Self-chain edges keep the flag
// wait (arrives just-in-time); L1's h1[t] flag is pre-satisfied (L0 leads).
__global__ __launch_bounds__(256, 1) void lstm_recur(
    const bf16* __restrict__ xbf, const bf16* __restrict__ wsw0, const bf16* __restrict__ wsw1,
    const float* __restrict__ bias0, const float* __restrict__ bias1,
    bf16* __restrict__ h1hist, bf16* __restrict__ h2hist, unsigned short* __restrict__ flg) {
  __shared__ char Wlds[131072];
  __shared__ float red[64][33];

  const int tid = threadIdx.x;
  const int bid = blockIdx.x;
  const int layer = bid >> 7;
  const int blk = bid & 127;
  const int lane = tid & 63;
  const int wid = tid >> 6;
  const int mh = wid & 1;
  const int kh = wid >> 1;
  const int q = lane >> 4;
  const int ml = lane & 15;
  const int colbase = blk * 8;
  const int row0 = mh * 32 + ml;        // mt=0 A-row
  const int row1 = mh * 32 + 16 + ml;   // mt=1 A-row

  { // weight slice -> LDS once
    const char* src = layer ? (const char*)wsw1 + (size_t)blk * 131072
                            : (const char*)wsw0 + (size_t)blk * 98304;
    const int nb = layer ? 131072 : 98304;
    for (int off = tid * 16; off < nb; off += 256 * 16)
      *(uint4*)(Wlds + off) = *(const uint4*)(src + off);
  }

  float biasv[2];
  {
    const float* bs = layer ? bias1 : bias0;
#pragma unroll
    for (int nt = 0; nt < 2; ++nt) {
      const int nl = nt * 16 + ml;
      biasv[nt] = bs[(nl >> 3) * 1024 + colbase + (nl & 7)];
    }
  }
  __syncthreads();

  float cstate[2] = {0.f, 0.f};
  const f32x4 zacc = {0.f, 0.f, 0.f, 0.f};
  const char* WldsC = Wlds;

  // flag base pointers (layer0 producers: slots 0..127; layer1: 128..255)
  const unsigned short* f_l0 = flg;                       // h1 producers
  const unsigned short* f_l1 = flg + ((size_t)128 << 9);  // h2 producers
  unsigned short* fme = flg + (((size_t)layer * 128 + blk) << 9);

  for (int t = 0; t < NT_T; ++t) {
    const bf16* h1prev = h1hist + (size_t)(t - 1) * SLOT_E;  // valid iff t>0
    const bf16* h1cur  = h1hist + (size_t)t * SLOT_E;
    const bf16* h2prev = h2hist + (size_t)(t - 1) * SLOT_E;  // valid iff t>0

    f32x4 acc[2][2];
#pragma unroll
    for (int a1 = 0; a1 < 2; ++a1)
#pragma unroll
      for (int a2 = 0; a2 < 2; ++a2) acc[a1][a2] = zacc;

    if (layer == 0) {
      // x loads go out first (plain; latency hides under the flag wait)
      const bf16* xb = xbf + (size_t)t * NB * NI;
      const int kx = kh * 256 + q * 8;
      bf16x8 Ax[8][2];
      load_batch<8>(Ax, xb + (size_t)row0 * NI + kx, xb + (size_t)row1 * NI + kx);
      if (t > 0) {
        // this wave's k-range needs producer blocks kh*64 .. kh*64+63
        waitf1(f_l0 + (((size_t)(kh * 64 + lane)) << 9) + (t - 1));
        const int khh = kh * 512 + q * 8;
        const bf16* hp0 = h1prev + (size_t)row0 * NH + khh;
        const bf16* hp1 = h1prev + (size_t)row1 * NH + khh;
        bf16x8 Ah[16][2];
        load_batch<16>(Ah, hp0, hp1);
        validate_tile<16>(Ah, hp0, hp1);   // hint flag => verify data
        mfma_batch<8, 48>(acc, Ax, WldsC, kh * 8, lane);
        mfma_batch<16, 48>(acc, Ah, WldsC, 16 + kh * 16, lane);
      } else {
        mfma_batch<8, 48>(acc, Ax, WldsC, kh * 8, lane);
      }
    } else {
      if (kh == 0) {
        waitf2(f_l0 + ((size_t)lane << 9) + t,
               f_l0 + (((size_t)(64 + lane)) << 9) + t);   // h1[t] (pre-satisfied)
        const bf16* hp0 = h1cur + (size_t)row0 * NH + q * 8;
        const bf16* hp1 = h1cur + (size_t)row1 * NH + q * 8;
        bf16x8 Ah[32][2];
        load_batch<32>(Ah, hp0, hp1);
        validate_tile<32>(Ah, hp0, hp1);
        mfma_batch<32, 64>(acc, Ah, WldsC, 0, lane);
      } else if (t > 0) {
        waitf2(f_l1 + ((size_t)lane << 9) + (t - 1),
               f_l1 + (((size_t)(64 + lane)) << 9) + (t - 1));  // h2[t-1] own pace
        const bf16* hp0 = h2prev + (size_t)row0 * NH + q * 8;
        const bf16* hp1 = h2prev + (size_t)row1 * NH + q * 8;
        bf16x8 Ah[32][2];
        load_batch<32>(Ah, hp0, hp1);
        validate_tile<32>(Ah, hp0, hp1);
        mfma_batch<32, 64>(acc, Ah, WldsC, 32, lane);
      }
    }

    // cross-kh reduction: kh==1 publishes partials, kh==0 combines + bias.
    if (kh == 1) {
#pragma unroll
      for (int mt = 0; mt < 2; ++mt)
#pragma unroll
        for (int nt = 0; nt < 2; ++nt)
#pragma unroll
          for (int r = 0; r < 4; ++r)
            red[mh * 32 + mt * 16 + q * 4 + r][nt * 16 + ml] = acc[mt][nt][r];
    }
    __syncthreads();
    if (kh == 0) {
#pragma unroll
      for (int mt = 0; mt < 2; ++mt)
#pragma unroll
        for (int nt = 0; nt < 2; ++nt)
#pragma unroll
          for (int r = 0; r < 4; ++r) {
            const int mloc = mh * 32 + mt * 16 + q * 4 + r;
            const int nloc = nt * 16 + ml;
            red[mloc][nloc] = acc[mt][nt][r] + red[mloc][nloc] + biasv[nt];
          }
    }
    __syncthreads();

    // elementwise LSTM cell: thread owns (b = tid>>2, cc0 = (tid&3)*2, +1) -> packed 4B store
    {
      const int b = tid >> 2;
      const int cc0 = (tid & 3) * 2;
      unsigned short hb[2];
#pragma unroll
      for (int e2 = 0; e2 < 2; ++e2) {
        const int cc = cc0 + e2;
        const float gi = red[b][cc];
        const float gf = red[b][8 + cc];
        const float gg = red[b][16 + cc];
        const float go = red[b][24 + cc];
        const float cn = sigm(gf) * cstate[e2] + sigm(gi) * tanh_fast(gg);
        cstate[e2] = cn;
        const float hv = sigm(go) * tanh_fast(cn);
        hb[e2] = __builtin_bit_cast(unsigned short, __float2bfloat16(hv));
      }
      const unsigned int packed = (unsigned int)hb[0] | ((unsigned int)hb[1] << 16);
      bf16* dstbase = (layer ? h2hist : h1hist) + (size_t)t * SLOT_E + (size_t)b * NH;
      __hip_atomic_store((unsigned int*)(dstbase + colbase + cc0), packed,
                         __ATOMIC_RELAXED, __HIP_MEMORY_SCOPE_AGENT);
    }

    // EARLY hint flag: fired before the end-of-step barrier, no drain. Other
    // waves' stores may still be in flight (skew ~ cell VALU time); consumers
    // sentinel-validate, so the flag only needs to be a good hint.
    if (tid == 0)
      __hip_atomic_store(fme + t, (unsigned short)1,
                         __ATOMIC_RELAXED, __HIP_MEMORY_SCOPE_AGENT);

    // end-of-step barrier: protects red[] reuse across steps.
    __syncthreads();
  }
}

// ---------------- output projection: h2hist(slots) @ W_out^T + b_out ----------------
// A-tile loads sentinel-validate too: consumer-side premature reads during the
// recurrence can leave stale-sentinel lines in some XCD's L2; repair via
// agent-scope dword loads (write-once addresses -> fresh at coherence point).
__global__ __launch_bounds__(256) void gemm_out(
    const bf16* __restrict__ A, const bf16* __restrict__ B,
    const float* __restrict__ bout, float* __restrict__ out) {
  __shared__ char As[8192];
  __shared__ char Bs[8192];
  const int tid = threadIdx.x;
  const int lane = tid & 63;
  const int wid = tid >> 6;
  const int wm = wid >> 1;
  const int wn = wid & 1;
  const size_t Mbase = (size_t)blockIdx.y * 128;
  const int Nbase = blockIdx.x * 128;

  const f32x4 zacc = {0.f, 0.f, 0.f, 0.f};
  f32x4 acc[4][4];
#pragma unroll
  for (int i = 0; i < 4; ++i)
#pragma unroll
    for (int j = 0; j < 4; ++j) acc[i][j] = zacc;

  for (int kc = 0; kc < 32; ++kc) {
    const int kb = kc * 32;
#pragma unroll
    for (int e = 0; e < 2; ++e) {
      const int id = e * 256 + tid;
      const int r = id >> 2;
      const int c8 = (id & 3) * 8;
      const int dst = ((r >> 4) * 64 + (c8 >> 3) * 16 + (r & 15)) * 16;
      const size_t m = Mbase + r;
      const bf16* arow = A + (m >> 6) * SLOT_E + (size_t)(m & 63) * NH;  // slot-aware row
      uint4 va = *(const uint4*)(arow + kb + c8);
      {  // sentinel repair (rare)
        const unsigned bad = (unsigned)(va.x == 0xFFFFFFFFu) | (unsigned)(va.y == 0xFFFFFFFFu) |
                             (unsigned)(va.z == 0xFFFFFFFFu) | (unsigned)(va.w == 0xFFFFFFFFu);
        if (__any(bad != 0)) {
          const unsigned* q = (const unsigned*)(arow + kb + c8);
          if (bad) {
            va.x = __hip_atomic_load(q + 0, __ATOMIC_RELAXED, __HIP_MEMORY_SCOPE_AGENT);
            va.y = __hip_atomic_load(q + 1, __ATOMIC_RELAXED, __HIP_MEMORY_SCOPE_AGENT);
            va.z = __hip_atomic_load(q + 2, __ATOMIC_RELAXED, __HIP_MEMORY_SCOPE_AGENT);
            va.w = __hip_atomic_load(q + 3, __ATOMIC_RELAXED, __HIP_MEMORY_SCOPE_AGENT);
          }
        }
      }
      *(uint4*)(As + dst) = va;
      *(uint4*)(Bs + dst) = *(const uint4*)(B + (size_t)(Nbase + r) * NH + kb + c8);
    }
    __syncthreads();
    bf16x8 af[4], bfr[4];
#pragma unroll
    for (int i = 0; i < 4; ++i) {
      af[i]  = *(const bf16x8*)(As + ((wm * 4 + i) * 64 + lane) * 16);
      bfr[i] = *(const bf16x8*)(Bs + ((wn * 4 + i) * 64 + lane) * 16);
    }
#pragma unroll
    for (int i = 0; i < 4; ++i)
#pragma unroll
      for (int j = 0; j < 4; ++j)
        acc[i][j] = __builtin_amdgcn_mfma_f32_16x16x32_bf16(af[i], bfr[j], acc[i][j], 0, 0, 0);
    __syncthreads();
  }
  const int qq = lane >> 4, ml = lane & 15;
#pragma unroll
  for (int i = 0; i < 4; ++i)
#pragma unroll
    for (int j = 0; j < 4; ++j)
#pragma unroll
      for (int r = 0; r < 4; ++r) {
        const size_t m = Mbase + wm * 64 + i * 16 + qq * 4 + r;
        const int n = Nbase + wn * 64 + j * 16 + ml;
        out[m * NO + n] = acc[i][j][r] + bout[n];
      }
}

// ---------------- host ----------------
extern "C" void kernel_launch(void* const* d_in, const int* in_sizes, int n_in,
                              void* d_out, int out_size, void* d_ws, size_t ws_size,
                              hipStream_t stream) {
  (void)in_sizes; (void)n_in; (void)out_size; (void)ws_size;
  const float* x    = (const float*)d_in[0];
  const float* Wih0 = (const float*)d_in[1];
  const float* Whh0 = (const float*)d_in[2];
  const float* bih0 = (const float*)d_in[3];
  const float* bhh0 = (const float*)d_in[4];
  const float* Wih1 = (const float*)d_in[5];
  const float* Whh1 = (const float*)d_in[6];
  const float* bih1 = (const float*)d_in[7];
  const float* bhh1 = (const float*)d_in[8];
  const float* Wout = (const float*)d_in[9];
  const float* bout = (const float*)d_in[10];
  float* out = (float*)d_out;
  char* ws = (char*)d_ws;

  bf16*  xbf    = (bf16*)(ws + OFF_XBF);
  bf16*  wsw0   = (bf16*)(ws + OFF_WSW0);
  bf16*  wsw1   = (bf16*)(ws + OFF_WSW1);
  bf16*  woutbf = (bf16*)(ws + OFF_WOUT);
  float* bias0  = (float*)(ws + OFF_B0);
  float* bias1  = (float*)(ws + OFF_B1);
  bf16*  h1hist = (bf16*)(ws + OFF_H1);
  bf16*  h2hist = (bf16*)(ws + OFF_H2);
  unsigned short* flg = (unsigned short*)(ws + OFF_FLG);

  k_convert_x<<<8192, 256, 0, stream>>>(x, xbf);
  k_fill<<<8192, 256, 0, stream>>>((u32x4*)(ws + OFF_H1), (SZ_H1 + SZ_H2) / 16);
  k_build_wsw<<<14336, 256, 0, stream>>>(Wih0, Whh0, Wih1, Whh1, wsw0, wsw1);
  k_small<<<2048, 256, 0, stream>>>(Wout, bih0, bhh0, bih1, bhh1, woutbf, bias0, bias1,
                                    (unsigned int*)flg);
  lstm_recur<<<256, 256, 0, stream>>>(xbf, wsw0, wsw1, bias0, bias1, h1hist, h2hist, flg);
  gemm_out<<<dim3(4, 256), 256, 0, stream>>>(h2hist, woutbf, bout, out);
}

// Round 9
// 5030.500 us; speedup vs baseline: 3.3187x; 3.3187x over previous
//
#include <hip/hip_runtime.h>
#include <hip/hip_bf16.h>
#include <cstdint>
#include <cstddef>

typedef short bf16x8 __attribute__((ext_vector_type(8)));
typedef float f32x4  __attribute__((ext_vector_type(4)));
typedef __hip_bfloat16 bf16;

#define NT_T 512
#define NB   64
#define NI   512
#define NH   1024
#define NO   512

// h history slots: 64x1024 bf16 + 128-element pad (slot-aligned, no line straddle)
static constexpr size_t SLOT_E = (size_t)NB * NH + 128;
static constexpr size_t SLOT_B = SLOT_E * 2;

// ---------------- workspace layout (bytes, all 256-aligned) ----------------
static constexpr size_t OFF_XBF   = 0;
static constexpr size_t SZ_XBF    = (size_t)NT_T * NB * NI * 2;
static constexpr size_t OFF_WSW0  = OFF_XBF + SZ_XBF;
static constexpr size_t SZ_WSW0   = 128ull * 98304;
static constexpr size_t OFF_WSW1  = OFF_WSW0 + SZ_WSW0;
static constexpr size_t SZ_WSW1   = 128ull * 131072;
static constexpr size_t OFF_WOUT  = OFF_WSW1 + SZ_WSW1;
static constexpr size_t SZ_WOUT   = (size_t)NO * NH * 2;
static constexpr size_t OFF_B0    = OFF_WOUT + SZ_WOUT;
static constexpr size_t OFF_B1    = OFF_B0 + 4096 * 4;
static constexpr size_t OFF_H1    = OFF_B1 + 4096 * 4;
static constexpr size_t SZ_H1     = (size_t)NT_T * SLOT_B;
static constexpr size_t OFF_H2    = OFF_H1 + SZ_H1;
static constexpr size_t SZ_H2     = (size_t)NT_T * SLOT_B;
// flags[layer(2)][blk(128)][t(512)] ushort: producer-private lines (R3-proven)
static constexpr size_t OFF_FLG   = OFF_H2 + SZ_H2;
static constexpr size_t SZ_FLG    = 2ull * 128 * 512 * 2;   // 256 KB
// total ~198.7 MB

__device__ __forceinline__ float sigm(float x) {
  return 1.0f / (1.0f + __expf(-x));
}
__device__ __forceinline__ float tanh_fast(float x) {
  x = fminf(15.0f, fmaxf(-15.0f, x));
  const float e = __expf(2.0f * x);
  return (e - 1.0f) / (e + 1.0f);
}

// Per-wave flag wait over producer-private slots (R3-proven form). Agent-scope
// loads are served fresh from the coherence point. Trailing compiler fence
// keeps subsequent cached bulk h-loads from hoisting above the observed flag.
__device__ __forceinline__ void waitf1(const unsigned short* f) {
  while (!__all(__hip_atomic_load(f, __ATOMIC_RELAXED, __HIP_MEMORY_SCOPE_AGENT) != 0))
    __builtin_amdgcn_s_sleep(1);
  asm volatile("" ::: "memory");
}

// plain batch load of N k-slices (2 row-fragments each) -- R3-proven codegen
template <int N>
__device__ __forceinline__ void load_batch(bf16x8 (&A)[N][2], const bf16* p0, const bf16* p1) {
#pragma unroll
  for (int i = 0; i < N; ++i) {
    A[i][0] = *(const bf16x8*)(p0 + i * 32);
    A[i][1] = *(const bf16x8*)(p1 + i * 32);
  }
}

template <int N, int KSW>
__device__ __forceinline__ void mfma_batch(f32x4 (&acc)[2][2], const bf16x8 (&A)[N][2],
                                           const char* Wlds, int ksbase, int lane) {
#pragma unroll
  for (int i = 0; i < N; ++i) {
#pragma unroll
    for (int nt = 0; nt < 2; ++nt) {
      const bf16x8 b = *(const bf16x8*)(Wlds + ((size_t)(nt * KSW + ksbase + i) * 64 + lane) * 16);
      acc[0][nt] = __builtin_amdgcn_mfma_f32_16x16x32_bf16(A[i][0], b, acc[0][nt], 0, 0, 0);
      acc[1][nt] = __builtin_amdgcn_mfma_f32_16x16x32_bf16(A[i][1], b, acc[1][nt], 0, 0, 0);
    }
  }
}

// ---------------- prep kernels ----------------
__global__ void k_convert_x(const float* __restrict__ x, bf16* __restrict__ xbf) {
  const size_t n = (size_t)NT_T * NB * NI;
  for (size_t i = (size_t)blockIdx.x * blockDim.x + threadIdx.x; i < n;
       i += (size_t)gridDim.x * blockDim.x)
    xbf[i] = __float2bfloat16(x[i]);
}

// Per-block, per-lane fragment-ordered weight images.
// B-fragment of mfma_f32_16x16x32_bf16: lane l holds B[n = l&15][k = (l>>4)*8 + j].
// Layout: [blk][nt(2)][ks][lane(64)][j(8)]; K-concat: L0 [W_ih0|W_hh0] ks 0..47,
// L1 [W_ih1|W_hh1] ks 0..63. Gate rows per block: [i f g o] x 8 cols at blk*8.
__global__ void k_build_wsw(const float* __restrict__ Wih0, const float* __restrict__ Whh0,
                            const float* __restrict__ Wih1, const float* __restrict__ Whh1,
                            bf16* __restrict__ wsw0, bf16* __restrict__ wsw1) {
  const size_t L0N = 128ull * 2 * 48 * 64 * 8;
  const size_t L1N = 128ull * 2 * 64 * 64 * 8;
  const size_t n = L0N + L1N;
  for (size_t i = (size_t)blockIdx.x * blockDim.x + threadIdx.x; i < n;
       i += (size_t)gridDim.x * blockDim.x) {
    if (i < L0N) {
      size_t idx = i;
      const int j = idx & 7;    idx >>= 3;
      const int lane = idx & 63; idx >>= 6;
      const int ks = (int)(idx % 48); idx /= 48;
      const int nt = idx & 1;
      const int blk = (int)(idx >> 1);
      const int nl = nt * 16 + (lane & 15);
      const int k = ks * 32 + (lane >> 4) * 8 + j;
      const int grow = (nl >> 3) * 1024 + blk * 8 + (nl & 7);
      const float v = (k < 512) ? Wih0[(size_t)grow * 512 + k]
                                : Whh0[(size_t)grow * 1024 + (k - 512)];
      wsw0[i] = __float2bfloat16(v);
    } else {
      size_t idx = i - L0N;
      const size_t o = idx;
      const int j = idx & 7;    idx >>= 3;
      const int lane = idx & 63; idx >>= 6;
      const int ks = (int)(idx % 64); idx /= 64;
      const int nt = idx & 1;
      const int blk = (int)(idx >> 1);
      const int nl = nt * 16 + (lane & 15);
      const int k = ks * 32 + (lane >> 4) * 8 + j;
      const int grow = (nl >> 3) * 1024 + blk * 8 + (nl & 7);
      const float v = (k < 1024) ? Wih1[(size_t)grow * 1024 + k]
                                 : Whh1[(size_t)grow * 1024 + (k - 1024)];
      wsw1[o] = __float2bfloat16(v);
    }
  }
}

__global__ void k_small(const float* __restrict__ Wout,
                        const float* __restrict__ bih0, const float* __restrict__ bhh0,
                        const float* __restrict__ bih1, const float* __restrict__ bhh1,
                        bf16* __restrict__ woutbf, float* __restrict__ bias0,
                        float* __restrict__ bias1, unsigned int* __restrict__ flg) {
  const int i = blockIdx.x * 256 + threadIdx.x;
  if (i < NO * NH) woutbf[i] = __float2bfloat16(Wout[i]);
  if (i < 4096) {
    bias0[i] = bih0[i] + bhh0[i];
    bias1[i] = bih1[i] + bhh1[i];
  }
  if (i < (int)(SZ_FLG / 4)) flg[i] = 0u;  // zero the flag region
}

// ---------------- persistent fused 2-layer LSTM recurrence ----------------
// grid = 256 x 512thr (8 waves), 1 block/CU. blocks 0..127: layer0, 128..255: L1.
// R3 protocol EXACTLY: producer-private flags flg[layer][blk][t], set by tid0
// after the end-of-step barrier (per-wave vmcnt(0) at the barrier drains agent
// h-stores to the coherence point -> flag implies data). Consumers poll only
// the flags they need.
// R9 delta (only change): each R3 wave's ks-range is SPLIT across a half
// dimension (hf) -> per-lane load depth halves (L1: 32->16, L0: 16->8 frags),
// so the compiler's ~10-load window covers the tile in ~1-2 miss epochs
// instead of 3-4. Waits narrow to each wave's true producer subset. The
// cross-kh reduction gains a third LDS slot dimension (3 publishers + 1
// combiner); barriers unchanged.
__global__ __launch_bounds__(512, 1) void lstm_recur(
    const bf16* __restrict__ xbf, const bf16* __restrict__ wsw0, const bf16* __restrict__ wsw1,
    const float* __restrict__ bias0, const float* __restrict__ bias1,
    bf16* __restrict__ h1hist, bf16* __restrict__ h2hist, unsigned short* __restrict__ flg) {
  __shared__ char Wlds[131072];
  __shared__ float red[3][64][33];   // publisher slots: (kh,hf)=(0,1)->0,(1,0)->1,(1,1)->2

  const int tid = threadIdx.x;
  const int bid = blockIdx.x;
  const int layer = bid >> 7;
  const int blk = bid & 127;
  const int lane = tid & 63;
  const int wid = tid >> 6;
  const int mh = wid & 1;          // row half (rows mh*32..+32)
  const int kh = (wid >> 1) & 1;   // k half / role
  const int hf = wid >> 2;         // NEW: quarter-split of the ks range
  const int q = lane >> 4;
  const int ml = lane & 15;
  const int colbase = blk * 8;
  const int row0 = mh * 32 + ml;        // mt=0 A-row
  const int row1 = mh * 32 + 16 + ml;   // mt=1 A-row
  const int slot = kh * 2 + hf - 1;     // publisher slot (-1 for combiner (0,0))

  { // weight slice -> LDS once
    const char* src = layer ? (const char*)wsw1 + (size_t)blk * 131072
                            : (const char*)wsw0 + (size_t)blk * 98304;
    const int nb = layer ? 131072 : 98304;
    for (int off = tid * 16; off < nb; off += 512 * 16)
      *(uint4*)(Wlds + off) = *(const uint4*)(src + off);
  }

  float biasv[2];
  {
    const float* bs = layer ? bias1 : bias0;
#pragma unroll
    for (int nt = 0; nt < 2; ++nt) {
      const int nl = nt * 16 + ml;
      biasv[nt] = bs[(nl >> 3) * 1024 + colbase + (nl & 7)];
    }
  }
  __syncthreads();

  float cstate[2] = {0.f, 0.f};
  const f32x4 zacc = {0.f, 0.f, 0.f, 0.f};
  const char* WldsC = Wlds;

  // flag base pointers (layer0 producers: slots 0..127; layer1: 128..255)
  const unsigned short* f_l0 = flg;                       // h1 producers
  const unsigned short* f_l1 = flg + ((size_t)128 << 9);  // h2 producers
  unsigned short* fme = flg + (((size_t)layer * 128 + blk) << 9);

  for (int t = 0; t < NT_T; ++t) {
    const bf16* h1prev = h1hist + (size_t)(t - 1) * SLOT_E;  // valid iff t>0
    const bf16* h1cur  = h1hist + (size_t)t * SLOT_E;
    const bf16* h2prev = h2hist + (size_t)(t - 1) * SLOT_E;  // valid iff t>0

    f32x4 acc[2][2];
#pragma unroll
    for (int a1 = 0; a1 < 2; ++a1)
#pragma unroll
      for (int a2 = 0; a2 < 2; ++a2) acc[a1][a2] = zacc;

    if (layer == 0) {
      // x loads go out first (plain; latency hides under the flag wait)
      const bf16* xb = xbf + (size_t)t * NB * NI;
      const int kx = kh * 256 + hf * 128 + q * 8;
      bf16x8 Ax[4][2];
      load_batch<4>(Ax, xb + (size_t)row0 * NI + kx, xb + (size_t)row1 * NI + kx);
      if (t > 0) {
        // this wave's h k-range [kh*512+hf*256, +256) -> 32 producer blocks
        waitf1(f_l0 + (((size_t)(kh * 64 + hf * 32 + (lane & 31))) << 9) + (t - 1));
        const int khh = kh * 512 + hf * 256 + q * 8;
        bf16x8 Ah[8][2];
        load_batch<8>(Ah, h1prev + (size_t)row0 * NH + khh,
                      h1prev + (size_t)row1 * NH + khh);
        __builtin_amdgcn_sched_barrier(0);
        mfma_batch<4, 48>(acc, Ax, WldsC, kh * 8 + hf * 4, lane);
        mfma_batch<8, 48>(acc, Ah, WldsC, 16 + kh * 16 + hf * 8, lane);
      } else {
        __builtin_amdgcn_sched_barrier(0);
        mfma_batch<4, 48>(acc, Ax, WldsC, kh * 8 + hf * 4, lane);
      }
    } else {
      if (kh == 0) {
        // h1[t], k-range [hf*512, +512) -> 64 producer blocks (pre-satisfied)
        waitf1(f_l0 + (((size_t)(hf * 64 + lane)) << 9) + t);
        const bf16* hp0 = h1cur + (size_t)row0 * NH + hf * 512 + q * 8;
        const bf16* hp1 = h1cur + (size_t)row1 * NH + hf * 512 + q * 8;
        bf16x8 Ah[16][2];
        load_batch<16>(Ah, hp0, hp1);
        __builtin_amdgcn_sched_barrier(0);
        mfma_batch<16, 64>(acc, Ah, WldsC, hf * 16, lane);
      } else if (t > 0) {
        // h2[t-1], k-range [hf*512, +512) -> 64 producer blocks (own pace)
        waitf1(f_l1 + (((size_t)(hf * 64 + lane)) << 9) + (t - 1));
        const bf16* hp0 = h2prev + (size_t)row0 * NH + hf * 512 + q * 8;
        const bf16* hp1 = h2prev + (size_t)row1 * NH + hf * 512 + q * 8;
        bf16x8 Ah[16][2];
        load_batch<16>(Ah, hp0, hp1);
        __builtin_amdgcn_sched_barrier(0);
        mfma_batch<16, 64>(acc, Ah, WldsC, 32 + hf * 16, lane);
      }
    }

    // cross-(kh,hf) reduction: 3 publishers write slots, combiner (0,0) sums.
    if (slot >= 0) {
#pragma unroll
      for (int mt = 0; mt < 2; ++mt)
#pragma unroll
        for (int nt = 0; nt < 2; ++nt)
#pragma unroll
          for (int r = 0; r < 4; ++r)
            red[slot][mh * 32 + mt * 16 + q * 4 + r][nt * 16 + ml] = acc[mt][nt][r];
    }
    __syncthreads();
    if (slot < 0) {
#pragma unroll
      for (int mt = 0; mt < 2; ++mt)
#pragma unroll
        for (int nt = 0; nt < 2; ++nt)
#pragma unroll
          for (int r = 0; r < 4; ++r) {
            const int mloc = mh * 32 + mt * 16 + q * 4 + r;
            const int nloc = nt * 16 + ml;
            red[0][mloc][nloc] = acc[mt][nt][r] + red[0][mloc][nloc] +
                                 red[1][mloc][nloc] + red[2][mloc][nloc] + biasv[nt];
          }
    }
    __syncthreads();

    // elementwise LSTM cell on waves 0-3: thread owns (b = tid>>2,
    // cc0 = (tid&3)*2, +1) -> packed 4B agent store
    if (tid < 256) {
      const int b = tid >> 2;
      const int cc0 = (tid & 3) * 2;
      unsigned short hb[2];
#pragma unroll
      for (int e2 = 0; e2 < 2; ++e2) {
        const int cc = cc0 + e2;
        const float gi = red[0][b][cc];
        const float gf = red[0][b][8 + cc];
        const float gg = red[0][b][16 + cc];
        const float go = red[0][b][24 + cc];
        const float cn = sigm(gf) * cstate[e2] + sigm(gi) * tanh_fast(gg);
        cstate[e2] = cn;
        const float hv = sigm(go) * tanh_fast(cn);
        hb[e2] = __builtin_bit_cast(unsigned short, __float2bfloat16(hv));
      }
      const unsigned int packed = (unsigned int)hb[0] | ((unsigned int)hb[1] << 16);
      bf16* dstbase = (layer ? h2hist : h1hist) + (size_t)t * SLOT_E + (size_t)b * NH;
      __hip_atomic_store((unsigned int*)(dstbase + colbase + cc0), packed,
                         __ATOMIC_RELAXED, __HIP_MEMORY_SCOPE_AGENT);
    }

    // end-of-step barrier: per-wave vmcnt(0) acks all agent h-stores at the
    // coherence point; then the producer-private flag store (fire-and-forget,
    // own cache line -> zero cross-producer serialization) publishes step t.
    __syncthreads();
    if (tid == 0)
      __hip_atomic_store(fme + t, (unsigned short)1,
                         __ATOMIC_RELAXED, __HIP_MEMORY_SCOPE_AGENT);
  }
}

// ---------------- output projection: h2hist(slots) @ W_out^T + b_out ----------------
__global__ __launch_bounds__(256) void gemm_out(
    const bf16* __restrict__ A, const bf16* __restrict__ B,
    const float* __restrict__ bout, float* __restrict__ out) {
  __shared__ char As[8192];
  __shared__ char Bs[8192];
  const int tid = threadIdx.x;
  const int lane = tid & 63;
  const int wid = tid >> 6;
  const int wm = wid >> 1;
  const int wn = wid & 1;
  const size_t Mbase = (size_t)blockIdx.y * 128;
  const int Nbase = blockIdx.x * 128;

  const f32x4 zacc = {0.f, 0.f, 0.f, 0.f};
  f32x4 acc[4][4];
#pragma unroll
  for (int i = 0; i < 4; ++i)
#pragma unroll
    for (int j = 0; j < 4; ++j) acc[i][j] = zacc;

  for (int kc = 0; kc < 32; ++kc) {
    const int kb = kc * 32;
#pragma unroll
    for (int e = 0; e < 2; ++e) {
      const int id = e * 256 + tid;
      const int r = id >> 2;
      const int c8 = (id & 3) * 8;
      const int dst = ((r >> 4) * 64 + (c8 >> 3) * 16 + (r & 15)) * 16;
      const size_t m = Mbase + r;
      const bf16* arow = A + (m >> 6) * SLOT_E + (size_t)(m & 63) * NH;  // slot-aware row
      *(uint4*)(As + dst) = *(const uint4*)(arow + kb + c8);
      *(uint4*)(Bs + dst) = *(const uint4*)(B + (size_t)(Nbase + r) * NH + kb + c8);
    }
    __syncthreads();
    bf16x8 af[4], bfr[4];
#pragma unroll
    for (int i = 0; i < 4; ++i) {
      af[i]  = *(const bf16x8*)(As + ((wm * 4 + i) * 64 + lane) * 16);
      bfr[i] = *(const bf16x8*)(Bs + ((wn * 4 + i) * 64 + lane) * 16);
    }
#pragma unroll
    for (int i = 0; i < 4; ++i)
#pragma unroll
      for (int j = 0; j < 4; ++j)
        acc[i][j] = __builtin_amdgcn_mfma_f32_16x16x32_bf16(af[i], bfr[j], acc[i][j], 0, 0, 0);
    __syncthreads();
  }
  const int qq = lane >> 4, ml = lane & 15;
#pragma unroll
  for (int i = 0; i < 4; ++i)
#pragma unroll
    for (int j = 0; j < 4; ++j)
#pragma unroll
      for (int r = 0; r < 4; ++r) {
        const size_t m = Mbase + wm * 64 + i * 16 + qq * 4 + r;
        const int n = Nbase + wn * 64 + j * 16 + ml;
        out[m * NO + n] = acc[i][j][r] + bout[n];
      }
}

// ---------------- host ----------------
extern "C" void kernel_launch(void* const* d_in, const int* in_sizes, int n_in,
                              void* d_out, int out_size, void* d_ws, size_t ws_size,
                              hipStream_t stream) {
  (void)in_sizes; (void)n_in; (void)out_size; (void)ws_size;
  const float* x    = (const float*)d_in[0];
  const float* Wih0 = (const float*)d_in[1];
  const float* Whh0 = (const float*)d_in[2];
  const float* bih0 = (const float*)d_in[3];
  const float* bhh0 = (const float*)d_in[4];
  const float* Wih1 = (const float*)d_in[5];
  const float* Whh1 = (const float*)d_in[6];
  const float* bih1 = (const float*)d_in[7];
  const float* bhh1 = (const float*)d_in[8];
  const float* Wout = (const float*)d_in[9];
  const float* bout = (const float*)d_in[10];
  float* out = (float*)d_out;
  char* ws = (char*)d_ws;

  bf16*  xbf    = (bf16*)(ws + OFF_XBF);
  bf16*  wsw0   = (bf16*)(ws + OFF_WSW0);
  bf16*  wsw1   = (bf16*)(ws + OFF_WSW1);
  bf16*  woutbf = (bf16*)(ws + OFF_WOUT);
  float* bias0  = (float*)(ws + OFF_B0);
  float* bias1  = (float*)(ws + OFF_B1);
  bf16*  h1hist = (bf16*)(ws + OFF_H1);
  bf16*  h2hist = (bf16*)(ws + OFF_H2);
  unsigned short* flg = (unsigned short*)(ws + OFF_FLG);

  k_convert_x<<<8192, 256, 0, stream>>>(x, xbf);
  k_build_wsw<<<14336, 256, 0, stream>>>(Wih0, Whh0, Wih1, Whh1, wsw0, wsw1);
  k_small<<<2048, 256, 0, stream>>>(Wout, bih0, bhh0, bih1, bhh1, woutbf, bias0, bias1,
                                    (unsigned int*)flg);
  lstm_recur<<<256, 512, 0, stream>>>(xbf, wsw0, wsw1, bias0, bias1, h1hist, h2hist, flg);
  gemm_out<<<dim3(4, 256), 256, 0, stream>>>(h2hist, woutbf, bout, out);
}